// Round 2
// baseline (7545.329 us; speedup 1.0000x reference)
//
#include <hip/hip_runtime.h>
#include <math.h>

// Mamba2-lite mixer, f32, ws-size-adaptive sequence chunking (round 2).
// B=4, L=4096, D_MODEL=1024, D_INNER=2048, D_CONV=4.

#define BATCH 4
#define SEQ 4096
#define DMODEL 1024
#define DINNER 2048
#define CLS 64          // within-chunk scan sub-length

#define BM 128
#define BN 128
#define BK 16

// ---- GEMM: C[m,n] = sum_k A[m,k]*W[n,k] (+bias[n]) --------------------
// Rows of A/C live in a [BATCH, rows_per_batch, K/N] layout; each block's
// BM rows stay inside one batch segment (Lc % BM == 0 guaranteed).
__global__ __launch_bounds__(256) void gemm_nt_bias(
    const float* __restrict__ A, const float* __restrict__ W,
    const float* __restrict__ bias, float* __restrict__ C,
    int K, int N, int Lc,
    int a_bstride, int a_l0, int c_bstride, int c_l0)
{
    __shared__ float As[BK][BM + 4];
    __shared__ float Bs[BK][BN + 4];
    const int tid = threadIdx.x;
    const int n0 = blockIdx.x * BN;
    const int m0 = blockIdx.y * BM;
    const int bb = m0 / Lc;
    const int lb = m0 - bb * Lc;
    const float* Arow0 = A + ((size_t)bb * a_bstride + a_l0 + lb) * K;
    float* Crow0 = C + ((size_t)bb * c_bstride + c_l0 + lb) * N;
    const int tx = tid & 15, ty = tid >> 4;

    float acc[8][8];
#pragma unroll
    for (int i = 0; i < 8; ++i)
#pragma unroll
        for (int j = 0; j < 8; ++j) acc[i][j] = 0.f;

    for (int k0 = 0; k0 < K; k0 += BK) {
#pragma unroll
        for (int r = 0; r < 2; ++r) {
            int idx = tid + r * 256;       // 0..511
            int row = idx >> 2;            // 0..127
            int c4  = (idx & 3) << 2;      // 0,4,8,12
            float4 va = *(const float4*)(Arow0 + (size_t)row * K + k0 + c4);
            As[c4 + 0][row] = va.x; As[c4 + 1][row] = va.y;
            As[c4 + 2][row] = va.z; As[c4 + 3][row] = va.w;
            float4 vb = *(const float4*)(W + (size_t)(n0 + row) * K + k0 + c4);
            Bs[c4 + 0][row] = vb.x; Bs[c4 + 1][row] = vb.y;
            Bs[c4 + 2][row] = vb.z; Bs[c4 + 3][row] = vb.w;
        }
        __syncthreads();
#pragma unroll
        for (int kk = 0; kk < BK; ++kk) {
            float a[8], b[8];
            *(float4*)&a[0] = *(const float4*)&As[kk][ty * 8];
            *(float4*)&a[4] = *(const float4*)&As[kk][ty * 8 + 4];
            *(float4*)&b[0] = *(const float4*)&Bs[kk][tx * 8];
            *(float4*)&b[4] = *(const float4*)&Bs[kk][tx * 8 + 4];
#pragma unroll
            for (int i = 0; i < 8; ++i)
#pragma unroll
                for (int j = 0; j < 8; ++j)
                    acc[i][j] = fmaf(a[i], b[j], acc[i][j]);
        }
        __syncthreads();
    }

#pragma unroll
    for (int i = 0; i < 8; ++i) {
        float* cp = Crow0 + (size_t)(ty * 8 + i) * N + n0 + tx * 8;
#pragma unroll
        for (int j = 0; j < 8; ++j) {
            float bv = bias ? bias[n0 + tx * 8 + j] : 0.f;
            cp[j] = acc[i][j] + bv;
        }
    }
}

// ---- causal depthwise conv1d (k=4) + SiLU, chunk-aware ----------------
__global__ __launch_bounds__(256) void conv_silu_chunk(
    const float* __restrict__ xb, const float* __restrict__ tail,
    const float* __restrict__ cw, const float* __restrict__ cb,
    float* __restrict__ u, int Lc, int l0, size_t total)
{
    for (size_t idx = (size_t)blockIdx.x * 256 + threadIdx.x; idx < total;
         idx += (size_t)gridDim.x * 256) {
        int e = (int)(idx % DINNER);
        size_t r = idx / DINNER;
        int lp = (int)(r % Lc);
        int b  = (int)(r / Lc);
        float4 w = *(const float4*)(cw + (size_t)e * 4);
        float s = cb[e];
        const float* xbase = xb + (size_t)b * Lc * DINNER + e;
        if (lp >= 3) {
            s += xbase[(size_t)(lp - 3) * DINNER] * w.x
               + xbase[(size_t)(lp - 2) * DINNER] * w.y
               + xbase[(size_t)(lp - 1) * DINNER] * w.z
               + xbase[(size_t)lp * DINNER] * w.w;
        } else {
            const float ws4[4] = {w.x, w.y, w.z, w.w};
            const float* tbase = tail + (size_t)b * 3 * DINNER + e;
#pragma unroll
            for (int j = 0; j < 4; ++j) {
                int ls = lp - 3 + j;
                float v;
                if (ls >= 0)            v = xbase[(size_t)ls * DINNER];
                else if (l0 + ls >= 0)  v = tbase[(size_t)(3 + ls) * DINNER];
                else                    v = 0.f;
                s += v * ws4[j];
            }
        }
        u[idx] = s / (1.f + expf(-s));
    }
}

// ---- save last 3 rows of x_branch per batch for next chunk's conv ------
__global__ __launch_bounds__(256) void tail_update_k(
    const float* __restrict__ xb, float* __restrict__ tail, int Lc)
{
    int idx = blockIdx.x * 256 + threadIdx.x;     // BATCH*3*DINNER = 24576
    if (idx >= BATCH * 3 * DINNER) return;
    int e = idx % DINNER;
    int j = (idx / DINNER) % 3;
    int b = idx / (3 * DINNER);
    tail[idx] = xb[((size_t)b * Lc + Lc - 3 + j) * DINNER + e];
}

// ---- pointwise: dt_raw->decay, b_raw->inc ------------------------------
__global__ __launch_bounds__(256) void pw1_k(
    float* __restrict__ dtbuf, float* __restrict__ bbuf,
    const float* __restrict__ u, const float* __restrict__ A_log, size_t total)
{
    for (size_t idx = (size_t)blockIdx.x * 256 + threadIdx.x; idx < total;
         idx += (size_t)gridDim.x * 256) {
        int e = (int)(idx % DINNER);
        float Ae = expf(A_log[e]);
        float xv = dtbuf[idx];
        float sp = fmaxf(xv, 0.f) + log1pf(expf(-fabsf(xv)));  // softplus
        float dt = sp + 1e-4f;
        float decay = expf(-dt * Ae);
        dtbuf[idx] = decay;
        bbuf[idx]  = (1.f - decay) * tanhf(bbuf[idx]) * u[idx];
    }
}

// ---- 3-phase chunked scan within an L-chunk, with carried state --------
__global__ __launch_bounds__(256) void scan_p1(
    const float* __restrict__ decay, const float* __restrict__ inc,
    float* __restrict__ P, float* __restrict__ S, int Lc, int nsub)
{
    int idx = blockIdx.x * 256 + threadIdx.x;   // BATCH*nsub*DINNER
    int e = idx % DINNER;
    int rest = idx / DINNER;
    int c = rest % nsub;
    int b = rest / nsub;
    size_t off = ((size_t)b * Lc + (size_t)c * CLS) * DINNER + e;
    float p = 1.f, s = 0.f;
    for (int t = 0; t < CLS; ++t) {
        float d = decay[off + (size_t)t * DINNER];
        float i = inc[off + (size_t)t * DINNER];
        s = d * s + i;
        p *= d;
    }
    P[idx] = p;
    S[idx] = s;
}

__global__ __launch_bounds__(256) void scan_p2(
    float* __restrict__ P, float* __restrict__ S,
    float* __restrict__ carry, int nsub, int first)
{
    int idx = blockIdx.x * 256 + threadIdx.x;   // BATCH*DINNER
    int e = idx % DINNER;
    int b = idx / DINNER;
    float cv = first ? 0.f : carry[idx];
    for (int c = 0; c < nsub; ++c) {
        size_t o = ((size_t)b * nsub + c) * DINNER + e;
        float p = P[o], s = S[o];
        P[o] = cv;                 // carry-in for sub-chunk c
        cv = p * cv + s;
    }
    carry[idx] = cv;               // state at end of this L-chunk
}

__global__ __launch_bounds__(256) void scan_p3(
    const float* __restrict__ decay, float* __restrict__ incst,
    const float* __restrict__ Pcarry, int Lc, int nsub)
{
    int idx = blockIdx.x * 256 + threadIdx.x;   // BATCH*nsub*DINNER
    int e = idx % DINNER;
    int rest = idx / DINNER;
    int c = rest % nsub;
    int b = rest / nsub;
    size_t off = ((size_t)b * Lc + (size_t)c * CLS) * DINNER + e;
    float st = Pcarry[idx];
    for (int t = 0; t < CLS; ++t) {
        size_t o = off + (size_t)t * DINNER;
        st = decay[o] * st + incst[o];
        incst[o] = st;             // states overwrite inc in place
    }
}

// ---- pointwise: y = tanh(c_raw)*state + D*u  (into state buffer) -------
__global__ __launch_bounds__(256) void pwy_k(
    const float* __restrict__ craw, float* __restrict__ st,
    const float* __restrict__ u, const float* __restrict__ Dp, size_t total)
{
    for (size_t idx = (size_t)blockIdx.x * 256 + threadIdx.x; idx < total;
         idx += (size_t)gridDim.x * 256) {
        int e = (int)(idx % DINNER);
        st[idx] = tanhf(craw[idx]) * st[idx] + Dp[e] * u[idx];
    }
}

// ---- pointwise: y *= sigmoid(z) ----------------------------------------
__global__ __launch_bounds__(256) void pwg_k(
    float* __restrict__ y, const float* __restrict__ z, size_t total)
{
    for (size_t idx = (size_t)blockIdx.x * 256 + threadIdx.x; idx < total;
         idx += (size_t)gridDim.x * 256) {
        y[idx] *= 1.f / (1.f + expf(-z[idx]));
    }
}

extern "C" void kernel_launch(void* const* d_in, const int* in_sizes, int n_in,
                              void* d_out, int out_size, void* d_ws, size_t ws_size,
                              hipStream_t stream)
{
    const float* x    = (const float*)d_in[0];   // [4,4096,1024]
    const float* ipw  = (const float*)d_in[1];   // [4096,1024]
    const float* ipb  = (const float*)d_in[2];   // [4096]
    const float* cw   = (const float*)d_in[3];   // [2048,1,4]
    const float* cb   = (const float*)d_in[4];   // [2048]
    const float* dtw  = (const float*)d_in[5];   // [2048,2048]
    const float* dtb  = (const float*)d_in[6];   // [2048]
    const float* bw   = (const float*)d_in[7];   // [2048,2048]
    const float* cwt  = (const float*)d_in[8];   // [2048,2048]
    const float* alog = (const float*)d_in[9];   // [2048]
    const float* dpar = (const float*)d_in[10];  // [2048]
    const float* ow   = (const float*)d_in[11];  // [1024,2048]
    const float* ob   = (const float*)d_in[12];  // [1024]
    float* out = (float*)d_out;

    // Pick largest L-chunk whose 3-buffer scratch fits ws_size.
    const size_t avail = ws_size / sizeof(float);
    const int cands[6] = {4096, 2048, 1024, 512, 256, 128};
    int Lc = 128;
    for (int i = 0; i < 6; ++i) {
        size_t NB = (size_t)BATCH * cands[i] * DINNER;
        size_t need = 3 * NB                                   // bufX,bufU,bufB
                    + (size_t)BATCH * 3 * DINNER               // conv tail
                    + (size_t)BATCH * DINNER                   // scan carry
                    + 2 * (size_t)BATCH * (cands[i] / CLS) * DINNER  // P,S
                    + 64;
        if (need <= avail) { Lc = cands[i]; break; }
    }
    const int nsub = Lc / CLS;
    const size_t NB = (size_t)BATCH * Lc * DINNER;

    float* bufX  = (float*)d_ws;                 // xb -> dt_raw/decay -> c_raw -> z
    float* bufU  = bufX + NB;                    // u
    float* bufB  = bufU + NB;                    // b_raw -> inc -> states -> y
    float* tail  = bufB + NB;                    // [BATCH,3,DINNER]
    float* carry = tail + (size_t)BATCH * 3 * DINNER;   // [BATCH,DINNER]
    float* Pb    = carry + (size_t)BATCH * DINNER;
    float* Sb    = Pb + (size_t)BATCH * nsub * DINNER;

    const int M = BATCH * Lc;
    const dim3 blk(256);
    const dim3 gInner(DINNER / BN, M / BM);
    const dim3 gOut(DMODEL / BN, M / BM);
    const int pwBlocks = (int)(((NB + 255) / 256 < 4096) ? (NB + 255) / 256 : 4096);
    const int scanBlocks = BATCH * nsub * DINNER / 256;

    const int nchunks = SEQ / Lc;
    for (int c = 0; c < nchunks; ++c) {
        const int l0 = c * Lc;
        // 1. x_branch chunk
        gemm_nt_bias<<<gInner, blk, 0, stream>>>(
            x, ipw, ipb, bufX, DMODEL, DINNER, Lc, SEQ, l0, Lc, 0);
        // 2. u = silu(conv(xb)) with tail from previous chunk
        conv_silu_chunk<<<pwBlocks, blk, 0, stream>>>(
            bufX, tail, cw, cb, bufU, Lc, l0, NB);
        // 2b. save tail for next chunk
        tail_update_k<<<BATCH * 3 * DINNER / 256, blk, 0, stream>>>(bufX, tail, Lc);
        // 3. dt_raw = u @ dt_w^T + dt_b
        gemm_nt_bias<<<gInner, blk, 0, stream>>>(
            bufU, dtw, dtb, bufX, DINNER, DINNER, Lc, Lc, 0, Lc, 0);
        // 4. b_raw = u @ b_w^T
        gemm_nt_bias<<<gInner, blk, 0, stream>>>(
            bufU, bw, nullptr, bufB, DINNER, DINNER, Lc, Lc, 0, Lc, 0);
        // 5. decay / inc
        pw1_k<<<pwBlocks, blk, 0, stream>>>(bufX, bufB, bufU, alog, NB);
        // 6. scan (states into bufB, carry across chunks)
        scan_p1<<<scanBlocks, blk, 0, stream>>>(bufX, bufB, Pb, Sb, Lc, nsub);
        scan_p2<<<BATCH * DINNER / 256, blk, 0, stream>>>(Pb, Sb, carry, nsub, c == 0);
        scan_p3<<<scanBlocks, blk, 0, stream>>>(bufX, bufB, Pb, Lc, nsub);
        // 7. c_raw = u @ c_w^T  (decay dead now)
        gemm_nt_bias<<<gInner, blk, 0, stream>>>(
            bufU, cwt, nullptr, bufX, DINNER, DINNER, Lc, Lc, 0, Lc, 0);
        // 8. y = tanh(c_raw)*states + D*u  (into bufB)
        pwy_k<<<pwBlocks, blk, 0, stream>>>(bufX, bufB, bufU, dpar, NB);
        // 9. z chunk
        gemm_nt_bias<<<gInner, blk, 0, stream>>>(
            x, ipw + (size_t)DINNER * DMODEL, ipb + DINNER, bufX,
            DMODEL, DINNER, Lc, SEQ, l0, Lc, 0);
        // 10. y *= sigmoid(z)
        pwg_k<<<pwBlocks, blk, 0, stream>>>(bufB, bufX, NB);
        // 11. out chunk = y @ out_w^T + out_b
        gemm_nt_bias<<<gOut, blk, 0, stream>>>(
            bufB, ow, ob, out, DINNER, DMODEL, Lc, Lc, 0, SEQ, l0);
    }
}

// Round 3
// 1335.523 us; speedup vs baseline: 5.6497x; 5.6497x over previous
//
#include <hip/hip_runtime.h>
#include <math.h>
#include <stdint.h>

// Mamba2-lite mixer, round 3: bf16 MFMA GEMMs + fused pointwise/scan.
// B=4, L=4096, D_MODEL=1024, D_INNER=2048, D_CONV=4.

#define BATCH 4
#define SEQ 4096
#define DMODEL 1024
#define DINNER 2048
#define CLS 64          // scan sub-chunk length

typedef __bf16 bf16_t;
typedef __bf16 bf16x8 __attribute__((ext_vector_type(8)));
typedef float f32x4 __attribute__((ext_vector_type(4)));

__device__ __forceinline__ void gload_lds16(const void* g, void* l) {
    __builtin_amdgcn_global_load_lds(
        (const __attribute__((address_space(1))) void*)g,
        (__attribute__((address_space(3))) void*)l, 16, 0, 0);
}

__device__ __forceinline__ unsigned short f2bf(float f) {
    union { float f; uint32_t u; } c; c.f = f;
    uint32_t u = c.u;
    u += 0x7fffu + ((u >> 16) & 1u);          // RNE
    return (unsigned short)(u >> 16);
}

__device__ __forceinline__ float tanh_fast(float v) {
    v = fminf(fmaxf(v, -15.f), 15.f);
    float e = __expf(2.f * v);
    return (e - 1.f) / (e + 1.f);
}

// ---------------- bf16 MFMA GEMM: C[m,n] = sum_k A[m,k]*W[n,k] (+bias) ---
// A: [M,K] bf16 row-major (batch-segmented rows), W: [N,K] bf16 row-major.
// 128x128 tile, BK=64, 4 waves (2x2 of 64x64), 16x16x32 MFMA.
// LDS rows are 128B; st_16x32-style XOR swizzle: byte ^= (row&7)<<4, applied
// as inverse-permuted GLOBAL source (linear global_load_lds dest) + swizzled
// ds_read (both-sides-or-neither, rule #21).
#define GBK 64

__global__ __launch_bounds__(256) void gemm_bf16(
    const bf16_t* __restrict__ A, const bf16_t* __restrict__ W,
    const float* __restrict__ bias, float* __restrict__ C,
    int K, int N, int Lc, int a_bstride, int a_l0, int c_bstride, int c_l0)
{
    __shared__ __align__(16) bf16_t sA[128 * GBK];   // 16 KB
    __shared__ __align__(16) bf16_t sB[128 * GBK];   // 16 KB
    const int tid = threadIdx.x;
    const int lane = tid & 63;
    const int wid = tid >> 6;
    const int wm = wid >> 1, wn = wid & 1;
    const int n0 = blockIdx.x * 128;
    const int m0 = blockIdx.y * 128;
    const int bb = m0 / Lc;
    const int lb = m0 - bb * Lc;
    const bf16_t* Abase = A + ((size_t)bb * a_bstride + a_l0 + lb) * K;
    const bf16_t* Wbase = W + (size_t)n0 * K;
    float* Cbase = C + ((size_t)bb * c_bstride + c_l0 + lb) * N + n0;

    // staging geometry: 256 thr x 16B = 4KB/issue = 32 rows; 4 issues/tile.
    int st_row[4], st_sc[4], st_ofs[4];
#pragma unroll
    for (int i = 0; i < 4; ++i) {
        int ofs = tid * 16 + i * 4096;
        int r = ofs >> 7;                  // dest row (128B rows)
        int c16 = (ofs >> 4) & 7;          // dest 16B-slot within row
        st_ofs[i] = ofs;
        st_row[i] = r;
        st_sc[i] = (c16 ^ (r & 7)) << 3;   // source col (bf16 units)
    }

    f32x4 acc[4][4];
#pragma unroll
    for (int i = 0; i < 4; ++i)
#pragma unroll
        for (int j = 0; j < 4; ++j) acc[i][j] = f32x4{0.f, 0.f, 0.f, 0.f};

    for (int k0 = 0; k0 < K; k0 += GBK) {
#pragma unroll
        for (int i = 0; i < 4; ++i) {
            gload_lds16(Abase + (size_t)st_row[i] * K + k0 + st_sc[i],
                        (char*)sA + st_ofs[i]);
            gload_lds16(Wbase + (size_t)st_row[i] * K + k0 + st_sc[i],
                        (char*)sB + st_ofs[i]);
        }
        __syncthreads();                   // drains vmcnt before barrier
#pragma unroll
        for (int ks = 0; ks < 2; ++ks) {
            bf16x8 av[4], bv[4];
#pragma unroll
            for (int mi = 0; mi < 4; ++mi) {
                int row = wm * 64 + mi * 16 + (lane & 15);
                int cb = (ks * 64 + ((lane >> 4) << 4)) ^ ((row & 7) << 4);
                av[mi] = *(const bf16x8*)((const char*)sA + row * 128 + cb);
            }
#pragma unroll
            for (int ni = 0; ni < 4; ++ni) {
                int row = wn * 64 + ni * 16 + (lane & 15);
                int cb = (ks * 64 + ((lane >> 4) << 4)) ^ ((row & 7) << 4);
                bv[ni] = *(const bf16x8*)((const char*)sB + row * 128 + cb);
            }
#pragma unroll
            for (int mi = 0; mi < 4; ++mi)
#pragma unroll
                for (int ni = 0; ni < 4; ++ni)
                    acc[mi][ni] = __builtin_amdgcn_mfma_f32_16x16x32_bf16(
                        av[mi], bv[ni], acc[mi][ni], 0, 0, 0);
        }
        __syncthreads();
    }

    float brow[4];
#pragma unroll
    for (int ni = 0; ni < 4; ++ni)
        brow[ni] = bias ? bias[n0 + wn * 64 + ni * 16 + (lane & 15)] : 0.f;
#pragma unroll
    for (int mi = 0; mi < 4; ++mi)
#pragma unroll
        for (int ni = 0; ni < 4; ++ni) {
            int coll = wn * 64 + ni * 16 + (lane & 15);
#pragma unroll
            for (int r4 = 0; r4 < 4; ++r4) {
                int rowl = wm * 64 + mi * 16 + ((lane >> 4) << 2) + r4;
                Cbase[(size_t)rowl * N + coll] = acc[mi][ni][r4] + brow[ni];
            }
        }
}

// ---------------- f32 -> bf16 conversion (vectorized) -------------------
__global__ __launch_bounds__(256) void cvt_bf16_k(
    const float4* __restrict__ in, ushort4* __restrict__ out, int n4)
{
    for (int i = blockIdx.x * 256 + threadIdx.x; i < n4;
         i += gridDim.x * 256) {
        float4 v = in[i];
        ushort4 o;
        o.x = f2bf(v.x); o.y = f2bf(v.y); o.z = f2bf(v.z); o.w = f2bf(v.w);
        out[i] = o;
    }
}

// ---------------- causal depthwise conv1d (k=4) + SiLU -> u(f32) + ubf ---
__global__ __launch_bounds__(256) void conv_silu_chunk(
    const float* __restrict__ xb, const float* __restrict__ tail,
    const float* __restrict__ cw, const float* __restrict__ cb,
    float* __restrict__ u, unsigned short* __restrict__ ubf,
    int Lc, int l0, size_t total)
{
    for (size_t idx = (size_t)blockIdx.x * 256 + threadIdx.x; idx < total;
         idx += (size_t)gridDim.x * 256) {
        int e = (int)(idx % DINNER);
        size_t r = idx / DINNER;
        int lp = (int)(r % Lc);
        int b  = (int)(r / Lc);
        float4 w = *(const float4*)(cw + (size_t)e * 4);
        float s = cb[e];
        const float* xbase = xb + (size_t)b * Lc * DINNER + e;
        if (lp >= 3) {
            s += xbase[(size_t)(lp - 3) * DINNER] * w.x
               + xbase[(size_t)(lp - 2) * DINNER] * w.y
               + xbase[(size_t)(lp - 1) * DINNER] * w.z
               + xbase[(size_t)lp * DINNER] * w.w;
        } else {
            const float ws4[4] = {w.x, w.y, w.z, w.w};
            const float* tbase = tail + (size_t)b * 3 * DINNER + e;
#pragma unroll
            for (int j = 0; j < 4; ++j) {
                int ls = lp - 3 + j;
                float v;
                if (ls >= 0)            v = xbase[(size_t)ls * DINNER];
                else if (l0 + ls >= 0)  v = tbase[(size_t)(3 + ls) * DINNER];
                else                    v = 0.f;
                s += v * ws4[j];
            }
        }
        float uu = s / (1.f + __expf(-s));
        u[idx] = uu;
        ubf[idx] = f2bf(uu);
    }
}

__global__ __launch_bounds__(256) void tail_update_k(
    const float* __restrict__ xb, float* __restrict__ tail, int Lc)
{
    int idx = blockIdx.x * 256 + threadIdx.x;     // BATCH*3*DINNER
    if (idx >= BATCH * 3 * DINNER) return;
    int e = idx % DINNER;
    int j = (idx / DINNER) % 3;
    int b = idx / (3 * DINNER);
    tail[idx] = xb[((size_t)b * Lc + Lc - 3 + j) * DINNER + e];
}

// ---------------- fused pw1 + scan phase1 -------------------------------
// in: dtd=dt_raw -> out decay; bi=b_raw -> out inc; writes P,S per sub-chunk.
__global__ __launch_bounds__(256) void pw1scan1_k(
    float* __restrict__ dtd, float* __restrict__ bi,
    const float* __restrict__ u, const float* __restrict__ A_log,
    float* __restrict__ P, float* __restrict__ S, int Lc, int nsub)
{
    int idx = blockIdx.x * 256 + threadIdx.x;   // BATCH*nsub*DINNER
    int e = idx % DINNER;
    int rest = idx / DINNER;
    int c = rest % nsub;
    int b = rest / nsub;
    size_t off = ((size_t)b * Lc + (size_t)c * CLS) * DINNER + e;
    float Ae = __expf(A_log[e]);
    float p = 1.f, s = 0.f;
    for (int t = 0; t < CLS; ++t) {
        size_t o = off + (size_t)t * DINNER;
        float xv = dtd[o];
        float sp = fmaxf(xv, 0.f) + __logf(1.f + __expf(-fabsf(xv)));
        float dt = sp + 1e-4f;
        float decay = __expf(-dt * Ae);
        float inc = (1.f - decay) * tanh_fast(bi[o]) * u[o];
        dtd[o] = decay;
        bi[o] = inc;
        s = decay * s + inc;
        p *= decay;
    }
    P[idx] = p;
    S[idx] = s;
}

__global__ __launch_bounds__(256) void scan_p2(
    float* __restrict__ P, float* __restrict__ S,
    float* __restrict__ carry, int nsub, int first)
{
    int idx = blockIdx.x * 256 + threadIdx.x;   // BATCH*DINNER
    int e = idx % DINNER;
    int b = idx / DINNER;
    float cv = first ? 0.f : carry[idx];
    for (int c = 0; c < nsub; ++c) {
        size_t o = ((size_t)b * nsub + c) * DINNER + e;
        float p = P[o], s = S[o];
        P[o] = cv;
        cv = p * cv + s;
    }
    carry[idx] = cv;
}

// ---------------- fused scan phase3 + y = tanh(craw)*state + D*u --------
__global__ __launch_bounds__(256) void p3y_k(
    const float* __restrict__ decay, float* __restrict__ incy,
    const float* __restrict__ craw, const float* __restrict__ u,
    const float* __restrict__ Dp, const float* __restrict__ Pc,
    int Lc, int nsub)
{
    int idx = blockIdx.x * 256 + threadIdx.x;   // BATCH*nsub*DINNER
    int e = idx % DINNER;
    int rest = idx / DINNER;
    int c = rest % nsub;
    int b = rest / nsub;
    size_t off = ((size_t)b * Lc + (size_t)c * CLS) * DINNER + e;
    float st = Pc[idx];
    float De = Dp[e];
    for (int t = 0; t < CLS; ++t) {
        size_t o = off + (size_t)t * DINNER;
        st = decay[o] * st + incy[o];
        incy[o] = tanh_fast(craw[o]) * st + De * u[o];
    }
}

// ---------------- gate + bf16 convert: ybf = bf16(y * sigmoid(z)) -------
__global__ __launch_bounds__(256) void gate_cvt_k(
    const float* __restrict__ y, const float* __restrict__ z,
    unsigned short* __restrict__ ybf, size_t total)
{
    for (size_t idx = (size_t)blockIdx.x * 256 + threadIdx.x; idx < total;
         idx += (size_t)gridDim.x * 256) {
        float g = y[idx] / (1.f + __expf(-z[idx]));
        ybf[idx] = f2bf(g);
    }
}

extern "C" void kernel_launch(void* const* d_in, const int* in_sizes, int n_in,
                              void* d_out, int out_size, void* d_ws, size_t ws_size,
                              hipStream_t stream)
{
    const float* x    = (const float*)d_in[0];   // [4,4096,1024]
    const float* ipw  = (const float*)d_in[1];   // [4096,1024]
    const float* ipb  = (const float*)d_in[2];   // [4096]
    const float* cw   = (const float*)d_in[3];   // [2048,1,4]
    const float* cb   = (const float*)d_in[4];   // [2048]
    const float* dtw  = (const float*)d_in[5];   // [2048,2048]
    const float* dtb  = (const float*)d_in[6];   // [2048]
    const float* bw   = (const float*)d_in[7];   // [2048,2048]
    const float* cwt  = (const float*)d_in[8];   // [2048,2048]
    const float* alog = (const float*)d_in[9];   // [2048]
    const float* dpar = (const float*)d_in[10];  // [2048]
    const float* ow   = (const float*)d_in[11];  // [1024,2048]
    const float* ob   = (const float*)d_in[12];  // [1024]
    float* out = (float*)d_out;

    const size_t XN   = (size_t)BATCH * SEQ * DMODEL;   // 16.7M
    const size_t WIP  = (size_t)2 * DINNER * DMODEL;    // 4.19M
    const size_t WSQ  = (size_t)DINNER * DINNER;        // 4.19M
    const size_t WOUT = (size_t)DMODEL * DINNER;        // 2.10M

    // ---- choose Lc adaptively (bytes) ----
    const int cands[5] = {2048, 1024, 512, 256, 128};
    const size_t const_bytes = 2 * (XN + WIP + 3 * WSQ + WOUT);  // xbf + weights
    int Lc = 128;
    for (int i = 0; i < 5; ++i) {
        size_t NBe = (size_t)BATCH * cands[i] * DINNER;
        size_t need = const_bytes
                    + 4 * NBe * 4                       // bufX,bufU,bufB,bufC f32
                    + NBe * 2                           // ubf/ybf
                    + (size_t)BATCH * 3 * DINNER * 4    // conv tail
                    + (size_t)BATCH * DINNER * 4        // scan carry
                    + 2 * (size_t)BATCH * (cands[i] / CLS) * DINNER * 4  // P,S
                    + 1024;
        if (need <= ws_size) { Lc = cands[i]; break; }
    }
    const int nsub = Lc / CLS;
    const size_t NBe = (size_t)BATCH * Lc * DINNER;

    // ---- workspace layout ----
    char* p = (char*)d_ws;
    unsigned short* xbf   = (unsigned short*)p; p += XN * 2;
    unsigned short* ipwbf = (unsigned short*)p; p += WIP * 2;
    unsigned short* dtwbf = (unsigned short*)p; p += WSQ * 2;
    unsigned short* bwbf  = (unsigned short*)p; p += WSQ * 2;
    unsigned short* cwtbf = (unsigned short*)p; p += WSQ * 2;
    unsigned short* owbf  = (unsigned short*)p; p += WOUT * 2;
    unsigned short* ubf   = (unsigned short*)p; p += NBe * 2;   // later ybf
    float* bufX  = (float*)p; p += NBe * 4;   // xb -> dt_raw/decay
    float* bufU  = (float*)p; p += NBe * 4;   // u
    float* bufB  = (float*)p; p += NBe * 4;   // b_raw -> inc -> y
    float* bufC  = (float*)p; p += NBe * 4;   // c_raw -> z
    float* tail  = (float*)p; p += (size_t)BATCH * 3 * DINNER * 4;
    float* carry = (float*)p; p += (size_t)BATCH * DINNER * 4;
    float* Pb    = (float*)p; p += (size_t)BATCH * nsub * DINNER * 4;
    float* Sb    = (float*)p;

    const dim3 blk(256);
    const int M = BATCH * Lc;
    const dim3 gInner(DINNER / 128, M / 128);
    const dim3 gOut(DMODEL / 128, M / 128);
    const int pwBlocks = (int)(((NBe + 255) / 256 < 4096) ? (NBe + 255) / 256 : 4096);
    const int scanBlocks = BATCH * nsub * DINNER / 256;

    // ---- one-time conversions ----
    auto cvt = [&](const float* in, unsigned short* outp, size_t n) {
        int n4 = (int)(n / 4);
        int g = n4 / 256 < 2048 ? (n4 + 255) / 256 : 2048;
        cvt_bf16_k<<<g, blk, 0, stream>>>((const float4*)in, (ushort4*)outp, n4);
    };
    cvt(x, xbf, XN);
    cvt(ipw, ipwbf, WIP);
    cvt(dtw, dtwbf, WSQ);
    cvt(bw, bwbf, WSQ);
    cvt(cwt, cwtbf, WSQ);
    cvt(ow, owbf, WOUT);

    const int nchunks = SEQ / Lc;
    for (int c = 0; c < nchunks; ++c) {
        const int l0 = c * Lc;
        // 1. x_branch = x @ ipw[0:2048]^T + b
        gemm_bf16<<<gInner, blk, 0, stream>>>(
            (const bf16_t*)xbf, (const bf16_t*)ipwbf, ipb, bufX,
            DMODEL, DINNER, Lc, SEQ, l0, Lc, 0);
        // 2. u = silu(conv(xb)) (+ubf)
        conv_silu_chunk<<<pwBlocks, blk, 0, stream>>>(
            bufX, tail, cw, cb, bufU, ubf, Lc, l0, NBe);
        tail_update_k<<<BATCH * 3 * DINNER / 256, blk, 0, stream>>>(bufX, tail, Lc);
        // 3. dt_raw
        gemm_bf16<<<gInner, blk, 0, stream>>>(
            (const bf16_t*)ubf, (const bf16_t*)dtwbf, dtb, bufX,
            DINNER, DINNER, Lc, Lc, 0, Lc, 0);
        // 4. b_raw
        gemm_bf16<<<gInner, blk, 0, stream>>>(
            (const bf16_t*)ubf, (const bf16_t*)bwbf, nullptr, bufB,
            DINNER, DINNER, Lc, Lc, 0, Lc, 0);
        // 5. decay/inc + per-sub-chunk (P,S)
        pw1scan1_k<<<scanBlocks, blk, 0, stream>>>(bufX, bufB, bufU, alog,
                                                   Pb, Sb, Lc, nsub);
        // 6. sequential combine across sub-chunks (+cross-chunk carry)
        scan_p2<<<BATCH * DINNER / 256, blk, 0, stream>>>(Pb, Sb, carry, nsub, c == 0);
        // 7. c_raw
        gemm_bf16<<<gInner, blk, 0, stream>>>(
            (const bf16_t*)ubf, (const bf16_t*)cwtbf, nullptr, bufC,
            DINNER, DINNER, Lc, Lc, 0, Lc, 0);
        // 8. states replay + y = tanh(craw)*st + D*u  (into bufB)
        p3y_k<<<scanBlocks, blk, 0, stream>>>(bufX, bufB, bufC, bufU, dpar,
                                              Pb, Lc, nsub);
        // 9. z
        gemm_bf16<<<gInner, blk, 0, stream>>>(
            (const bf16_t*)xbf, (const bf16_t*)(ipwbf + (size_t)DINNER * DMODEL),
            ipb + DINNER, bufC, DMODEL, DINNER, Lc, SEQ, l0, Lc, 0);
        // 10. ybf = bf16(y * sigmoid(z))  (into ubf slot, dead now)
        gate_cvt_k<<<pwBlocks, blk, 0, stream>>>(bufB, bufC, ubf, NBe);
        // 11. out = ybf @ ow^T + ob
        gemm_bf16<<<gOut, blk, 0, stream>>>(
            (const bf16_t*)ubf, (const bf16_t*)owbf, ob, out,
            DINNER, DMODEL, Lc, Lc, 0, SEQ, l0);
    }
}

// Round 4
// 1310.255 us; speedup vs baseline: 5.7587x; 1.0193x over previous
//
#include <hip/hip_runtime.h>
#include <math.h>
#include <stdint.h>

// Mamba2-lite mixer, round 4: all-bf16 activations, pointwise fused into
// GEMM epilogues, vectorized bf16 scan. B=4,L=4096,Dm=1024,Di=2048,K=4.

#define BATCH 4
#define SEQ 4096
#define DMODEL 1024
#define DINNER 2048
#define CLS 64          // scan sub-chunk length

typedef __bf16 bf16_t;
typedef __bf16 bf16x8 __attribute__((ext_vector_type(8)));
typedef float f32x4 __attribute__((ext_vector_type(4)));
typedef unsigned short ushort_t;
typedef unsigned short u16x4 __attribute__((ext_vector_type(4)));

enum { EP_F32 = 0, EP_BF = 1, EP_DT = 2, EP_B = 3, EP_TANH = 4, EP_SIG = 5 };

__device__ __forceinline__ void gload_lds16(const void* g, void* l) {
    __builtin_amdgcn_global_load_lds(
        (const __attribute__((address_space(1))) void*)g,
        (__attribute__((address_space(3))) void*)l, 16, 0, 0);
}

__device__ __forceinline__ ushort_t f2bf(float f) {
    union { float f; uint32_t u; } c; c.f = f;
    uint32_t u = c.u;
    u += 0x7fffu + ((u >> 16) & 1u);          // RNE
    return (ushort_t)(u >> 16);
}
__device__ __forceinline__ float bf2f(ushort_t h) {
    union { uint32_t u; float f; } c; c.u = (uint32_t)h << 16;
    return c.f;
}
__device__ __forceinline__ float tanh_fast(float v) {
    v = fminf(fmaxf(v, -15.f), 15.f);
    float e = __expf(2.f * v);
    return (e - 1.f) / (e + 1.f);
}

// ---------------- bf16 MFMA GEMM with fused epilogues --------------------
// C[m,n] = sum_k A[m,k]*W[n,k] (+bias). 128x128 tile, BK=64, 4 waves,
// 16x16x32 MFMA, XOR-swizzled LDS via pre-swizzled global source.
#define GBK 64

__global__ __launch_bounds__(256) void gemm_bf16_ep(
    const bf16_t* __restrict__ A, const bf16_t* __restrict__ W,
    const float* __restrict__ bias,
    float* __restrict__ Cf, ushort_t* __restrict__ Cb,
    const ushort_t* __restrict__ decp, const ushort_t* __restrict__ ubp,
    const float* __restrict__ alogp,
    int K, int N, int Lc, int a_bstride, int a_l0, int c_bstride, int c_l0,
    int mode)
{
    __shared__ __align__(16) bf16_t sA[128 * GBK];   // 16 KB
    __shared__ __align__(16) bf16_t sB[128 * GBK];   // 16 KB
    const int tid = threadIdx.x;
    const int lane = tid & 63;
    const int wid = tid >> 6;
    const int wm = wid >> 1, wn = wid & 1;
    const int n0 = blockIdx.x * 128;
    const int m0 = blockIdx.y * 128;
    const int bb = m0 / Lc;
    const int lb = m0 - bb * Lc;
    const bf16_t* Abase = A + ((size_t)bb * a_bstride + a_l0 + lb) * K;
    const bf16_t* Wbase = W + (size_t)n0 * K;
    const size_t coff = ((size_t)bb * c_bstride + c_l0 + lb) * (size_t)N + n0;

    int st_row[4], st_sc[4], st_ofs[4];
#pragma unroll
    for (int i = 0; i < 4; ++i) {
        int ofs = tid * 16 + i * 4096;
        int r = ofs >> 7;
        int c16 = (ofs >> 4) & 7;
        st_ofs[i] = ofs;
        st_row[i] = r;
        st_sc[i] = (c16 ^ (r & 7)) << 3;
    }

    f32x4 acc[4][4];
#pragma unroll
    for (int i = 0; i < 4; ++i)
#pragma unroll
        for (int j = 0; j < 4; ++j) acc[i][j] = f32x4{0.f, 0.f, 0.f, 0.f};

    for (int k0 = 0; k0 < K; k0 += GBK) {
#pragma unroll
        for (int i = 0; i < 4; ++i) {
            gload_lds16(Abase + (size_t)st_row[i] * K + k0 + st_sc[i],
                        (char*)sA + st_ofs[i]);
            gload_lds16(Wbase + (size_t)st_row[i] * K + k0 + st_sc[i],
                        (char*)sB + st_ofs[i]);
        }
        __syncthreads();
#pragma unroll
        for (int ks = 0; ks < 2; ++ks) {
            bf16x8 av[4], bv[4];
#pragma unroll
            for (int mi = 0; mi < 4; ++mi) {
                int row = wm * 64 + mi * 16 + (lane & 15);
                int cb = (ks * 64 + ((lane >> 4) << 4)) ^ ((row & 7) << 4);
                av[mi] = *(const bf16x8*)((const char*)sA + row * 128 + cb);
            }
#pragma unroll
            for (int ni = 0; ni < 4; ++ni) {
                int row = wn * 64 + ni * 16 + (lane & 15);
                int cb = (ks * 64 + ((lane >> 4) << 4)) ^ ((row & 7) << 4);
                bv[ni] = *(const bf16x8*)((const char*)sB + row * 128 + cb);
            }
#pragma unroll
            for (int mi = 0; mi < 4; ++mi)
#pragma unroll
                for (int ni = 0; ni < 4; ++ni)
                    acc[mi][ni] = __builtin_amdgcn_mfma_f32_16x16x32_bf16(
                        av[mi], bv[ni], acc[mi][ni], 0, 0, 0);
        }
        __syncthreads();
    }

    // ---- fused epilogue ----
#pragma unroll
    for (int ni = 0; ni < 4; ++ni) {
        const int coll = wn * 64 + ni * 16 + (lane & 15);
        const float bv = bias ? bias[n0 + coll] : 0.f;
        const float Ae = (mode == EP_DT) ? __expf(alogp[n0 + coll]) : 0.f;
#pragma unroll
        for (int mi = 0; mi < 4; ++mi) {
#pragma unroll
            for (int r4 = 0; r4 < 4; ++r4) {
                const int rowl = wm * 64 + mi * 16 + ((lane >> 4) << 2) + r4;
                const size_t off = coff + (size_t)rowl * N + coll;
                float v = acc[mi][ni][r4] + bv;
                if (mode == EP_F32) {
                    Cf[off] = v;
                } else if (mode == EP_BF) {
                    Cb[off] = f2bf(v);
                } else if (mode == EP_DT) {
                    float sp = fmaxf(v, 0.f) + __logf(1.f + __expf(-fabsf(v)));
                    Cb[off] = f2bf(__expf(-(sp + 1e-4f) * Ae));
                } else if (mode == EP_B) {
                    float d = bf2f(decp[off]);
                    Cb[off] = f2bf((1.f - d) * tanh_fast(v) * bf2f(ubp[off]));
                } else if (mode == EP_TANH) {
                    Cb[off] = f2bf(tanh_fast(v));
                } else {  // EP_SIG
                    Cb[off] = f2bf(1.f / (1.f + __expf(-v)));
                }
            }
        }
    }
}

// ---------------- f32 -> bf16 conversion (one-time, inputs/weights) -----
__global__ __launch_bounds__(256) void cvt_bf16_k(
    const float4* __restrict__ in, ushort4* __restrict__ out, int n4)
{
    for (int i = blockIdx.x * 256 + threadIdx.x; i < n4; i += gridDim.x * 256) {
        float4 v = in[i];
        ushort4 o;
        o.x = f2bf(v.x); o.y = f2bf(v.y); o.z = f2bf(v.z); o.w = f2bf(v.w);
        out[i] = o;
    }
}

// ---------------- causal depthwise conv1d (k=4) + SiLU, bf16 in/out -----
__global__ __launch_bounds__(256) void conv_silu_bf(
    const ushort_t* __restrict__ xb, const ushort_t* __restrict__ tailb,
    const float* __restrict__ cw, const float* __restrict__ cb,
    ushort_t* __restrict__ ubf, int Lc, int l0, size_t total)
{
    for (size_t idx = (size_t)blockIdx.x * 256 + threadIdx.x; idx < total;
         idx += (size_t)gridDim.x * 256) {
        int e = (int)(idx % DINNER);
        size_t r = idx / DINNER;
        int lp = (int)(r % Lc);
        int b  = (int)(r / Lc);
        float4 w = *(const float4*)(cw + (size_t)e * 4);
        float s = cb[e];
        const ushort_t* xbase = xb + (size_t)b * Lc * DINNER + e;
        if (lp >= 3) {
            s += bf2f(xbase[(size_t)(lp - 3) * DINNER]) * w.x
               + bf2f(xbase[(size_t)(lp - 2) * DINNER]) * w.y
               + bf2f(xbase[(size_t)(lp - 1) * DINNER]) * w.z
               + bf2f(xbase[(size_t)lp * DINNER]) * w.w;
        } else {
            const float ws4[4] = {w.x, w.y, w.z, w.w};
            const ushort_t* tbase = tailb + (size_t)b * 3 * DINNER + e;
#pragma unroll
            for (int j = 0; j < 4; ++j) {
                int ls = lp - 3 + j;
                float v;
                if (ls >= 0)            v = bf2f(xbase[(size_t)ls * DINNER]);
                else if (l0 + ls >= 0)  v = bf2f(tbase[(size_t)(3 + ls) * DINNER]);
                else                    v = 0.f;
                s += v * ws4[j];
            }
        }
        ubf[idx] = f2bf(s / (1.f + __expf(-s)));
    }
}

__global__ __launch_bounds__(256) void tail_update_bf(
    const ushort_t* __restrict__ xb, ushort_t* __restrict__ tailb, int Lc)
{
    int idx = blockIdx.x * 256 + threadIdx.x;     // BATCH*3*DINNER
    if (idx >= BATCH * 3 * DINNER) return;
    int e = idx % DINNER;
    int j = (idx / DINNER) % 3;
    int b = idx / (3 * DINNER);
    tailb[idx] = xb[((size_t)b * Lc + Lc - 3 + j) * DINNER + e];
}

// ---------------- scan phase1: per-sub-chunk (prod, local-final), x4 ----
__global__ __launch_bounds__(256) void scan1_v4(
    const ushort_t* __restrict__ dec, const ushort_t* __restrict__ inc,
    float* __restrict__ P, float* __restrict__ S, int Lc, int nsub)
{
    int t = blockIdx.x * 256 + threadIdx.x;    // BATCH*nsub*512 threads
    int e = (t & 511) << 2;                    // 0..2044 step 4
    int rest = t >> 9;
    int c = rest % nsub;
    int b = rest / nsub;
    size_t off = ((size_t)b * Lc + (size_t)c * CLS) * DINNER + e;
    float p[4] = {1.f, 1.f, 1.f, 1.f};
    float s[4] = {0.f, 0.f, 0.f, 0.f};
    for (int t0 = 0; t0 < CLS; ++t0) {
        size_t o = off + (size_t)t0 * DINNER;
        u16x4 d4 = *(const u16x4*)(dec + o);
        u16x4 i4 = *(const u16x4*)(inc + o);
#pragma unroll
        for (int j = 0; j < 4; ++j) {
            float d = bf2f(d4[j]);
            s[j] = d * s[j] + bf2f(i4[j]);
            p[j] *= d;
        }
    }
    size_t po = ((size_t)b * nsub + c) * DINNER + e;
    *(float4*)(P + po) = float4{p[0], p[1], p[2], p[3]};
    *(float4*)(S + po) = float4{s[0], s[1], s[2], s[3]};
}

// ---------------- scan phase2: sequential combine over sub-chunks -------
__global__ __launch_bounds__(256) void scan_p2(
    float* __restrict__ P, float* __restrict__ S,
    float* __restrict__ carry, int nsub, int first)
{
    int idx = blockIdx.x * 256 + threadIdx.x;   // BATCH*DINNER
    int e = idx % DINNER;
    int b = idx / DINNER;
    float cv = first ? 0.f : carry[idx];
    for (int c = 0; c < nsub; ++c) {
        size_t o = ((size_t)b * nsub + c) * DINNER + e;
        float p = P[o], s = S[o];
        P[o] = cv;
        cv = p * cv + s;
    }
    carry[idx] = cv;
}

// ---------------- phase3 fused: replay + y = ct*st + D*u, gate, ->bf16 --
// inc buffer is overwritten in place with ybf.
__global__ __launch_bounds__(256) void p3y_v4(
    const ushort_t* __restrict__ dec, ushort_t* __restrict__ incy,
    const ushort_t* __restrict__ ct, const ushort_t* __restrict__ ub,
    const ushort_t* __restrict__ sg, const float* __restrict__ Dp,
    const float* __restrict__ Pc, int Lc, int nsub)
{
    int t = blockIdx.x * 256 + threadIdx.x;    // BATCH*nsub*512 threads
    int e = (t & 511) << 2;
    int rest = t >> 9;
    int c = rest % nsub;
    int b = rest / nsub;
    size_t off = ((size_t)b * Lc + (size_t)c * CLS) * DINNER + e;
    size_t po = ((size_t)b * nsub + c) * DINNER + e;
    float4 stv = *(const float4*)(Pc + po);
    float4 Dv  = *(const float4*)(Dp + e);
    float st[4] = {stv.x, stv.y, stv.z, stv.w};
    float D4[4] = {Dv.x, Dv.y, Dv.z, Dv.w};
    for (int t0 = 0; t0 < CLS; ++t0) {
        size_t o = off + (size_t)t0 * DINNER;
        u16x4 d4 = *(const u16x4*)(dec + o);
        u16x4 i4 = *(const u16x4*)(incy + o);
        u16x4 c4 = *(const u16x4*)(ct + o);
        u16x4 u4 = *(const u16x4*)(ub + o);
        u16x4 g4 = *(const u16x4*)(sg + o);
        u16x4 y4;
#pragma unroll
        for (int j = 0; j < 4; ++j) {
            st[j] = bf2f(d4[j]) * st[j] + bf2f(i4[j]);
            float y = bf2f(c4[j]) * st[j] + D4[j] * bf2f(u4[j]);
            y4[j] = f2bf(y * bf2f(g4[j]));
        }
        *(u16x4*)(incy + o) = y4;
    }
}

extern "C" void kernel_launch(void* const* d_in, const int* in_sizes, int n_in,
                              void* d_out, int out_size, void* d_ws, size_t ws_size,
                              hipStream_t stream)
{
    const float* x    = (const float*)d_in[0];
    const float* ipw  = (const float*)d_in[1];
    const float* ipb  = (const float*)d_in[2];
    const float* cw   = (const float*)d_in[3];
    const float* cb   = (const float*)d_in[4];
    const float* dtw  = (const float*)d_in[5];
    const float* dtb  = (const float*)d_in[6];
    const float* bw   = (const float*)d_in[7];
    const float* cwt  = (const float*)d_in[8];
    const float* alog = (const float*)d_in[9];
    const float* dpar = (const float*)d_in[10];
    const float* ow   = (const float*)d_in[11];
    const float* ob   = (const float*)d_in[12];
    float* out = (float*)d_out;

    const size_t XN   = (size_t)BATCH * SEQ * DMODEL;
    const size_t WIP  = (size_t)2 * DINNER * DMODEL;
    const size_t WSQ  = (size_t)DINNER * DINNER;
    const size_t WOUT = (size_t)DMODEL * DINNER;
    const size_t const_bytes = 2 * (XN + WIP + 3 * WSQ + WOUT);

    // ---- choose Lc (5 bf16 activation slots + scan partials) ----
    const int cands[6] = {4096, 2048, 1024, 512, 256, 128};
    int Lc = 128;
    for (int i = 0; i < 6; ++i) {
        size_t NBe = (size_t)BATCH * cands[i] * DINNER;
        size_t need = const_bytes
                    + 5 * NBe * 2
                    + (size_t)BATCH * 3 * DINNER * 2
                    + (size_t)BATCH * DINNER * 4
                    + 2 * (size_t)BATCH * (cands[i] / CLS) * DINNER * 4
                    + 1024;
        if (need <= ws_size) { Lc = cands[i]; break; }
    }
    const int nsub = Lc / CLS;
    const size_t NBe = (size_t)BATCH * Lc * DINNER;

    // ---- workspace layout ----
    char* p = (char*)d_ws;
    ushort_t* xbf   = (ushort_t*)p; p += XN * 2;
    ushort_t* ipwbf = (ushort_t*)p; p += WIP * 2;
    ushort_t* dtwbf = (ushort_t*)p; p += WSQ * 2;
    ushort_t* bwbf  = (ushort_t*)p; p += WSQ * 2;
    ushort_t* cwtbf = (ushort_t*)p; p += WSQ * 2;
    ushort_t* owbf  = (ushort_t*)p; p += WOUT * 2;
    ushort_t* S1 = (ushort_t*)p; p += NBe * 2;   // xb -> ct
    ushort_t* S2 = (ushort_t*)p; p += NBe * 2;   // ubf
    ushort_t* S3 = (ushort_t*)p; p += NBe * 2;   // decay
    ushort_t* S4 = (ushort_t*)p; p += NBe * 2;   // inc -> ybf
    ushort_t* S5 = (ushort_t*)p; p += NBe * 2;   // sigmoid(z)
    ushort_t* tailb = (ushort_t*)p; p += (size_t)BATCH * 3 * DINNER * 2;
    float* carry = (float*)p; p += (size_t)BATCH * DINNER * 4;
    float* Pb    = (float*)p; p += (size_t)BATCH * nsub * DINNER * 4;
    float* Sb    = (float*)p;

    const dim3 blk(256);
    const int M = BATCH * Lc;
    const dim3 gInner(DINNER / 128, M / 128);
    const dim3 gOut(DMODEL / 128, M / 128);
    const int pwBlocks = (int)(((NBe + 255) / 256 < 4096) ? (NBe + 255) / 256 : 4096);
    const int scanBlocks = BATCH * nsub * 2;     // x4 vectorized

    auto cvt = [&](const float* in, ushort_t* outp, size_t n) {
        int n4 = (int)(n / 4);
        int g = n4 / 256 < 2048 ? (n4 + 255) / 256 : 2048;
        cvt_bf16_k<<<g, blk, 0, stream>>>((const float4*)in, (ushort4*)outp, n4);
    };
    cvt(x, xbf, XN);
    cvt(ipw, ipwbf, WIP);
    cvt(dtw, dtwbf, WSQ);
    cvt(bw, bwbf, WSQ);
    cvt(cwt, cwtbf, WSQ);
    cvt(ow, owbf, WOUT);

    const int nchunks = SEQ / Lc;
    for (int c = 0; c < nchunks; ++c) {
        const int l0 = c * Lc;
        // 1. x_branch -> bf16
        gemm_bf16_ep<<<gInner, blk, 0, stream>>>(
            (const bf16_t*)xbf, (const bf16_t*)ipwbf, ipb, nullptr, S1,
            nullptr, nullptr, nullptr,
            DMODEL, DINNER, Lc, SEQ, l0, Lc, 0, EP_BF);
        // 2. u = silu(conv(xb))
        conv_silu_bf<<<pwBlocks, blk, 0, stream>>>(S1, tailb, cw, cb, S2, Lc, l0, NBe);
        tail_update_bf<<<BATCH * 3 * DINNER / 256, blk, 0, stream>>>(S1, tailb, Lc);
        // 3. decay = exp(-(softplus(u@dtw+dtb)+1e-4)*A)  [epilogue]
        gemm_bf16_ep<<<gInner, blk, 0, stream>>>(
            (const bf16_t*)S2, (const bf16_t*)dtwbf, dtb, nullptr, S3,
            nullptr, nullptr, alog,
            DINNER, DINNER, Lc, Lc, 0, Lc, 0, EP_DT);
        // 4. inc = (1-decay)*tanh(u@bw)*u  [epilogue]
        gemm_bf16_ep<<<gInner, blk, 0, stream>>>(
            (const bf16_t*)S2, (const bf16_t*)bwbf, nullptr, nullptr, S4,
            S3, S2, nullptr,
            DINNER, DINNER, Lc, Lc, 0, Lc, 0, EP_B);
        // 5-6. scan partials + combine
        scan1_v4<<<scanBlocks, blk, 0, stream>>>(S3, S4, Pb, Sb, Lc, nsub);
        scan_p2<<<BATCH * DINNER / 256, blk, 0, stream>>>(Pb, Sb, carry, nsub, c == 0);
        // 7. ct = tanh(u@cw)  [epilogue]
        gemm_bf16_ep<<<gInner, blk, 0, stream>>>(
            (const bf16_t*)S2, (const bf16_t*)cwtbf, nullptr, nullptr, S1,
            nullptr, nullptr, nullptr,
            DINNER, DINNER, Lc, Lc, 0, Lc, 0, EP_TANH);
        // 8. sig = sigmoid(x@ipw_z + b_z)  [epilogue]
        gemm_bf16_ep<<<gInner, blk, 0, stream>>>(
            (const bf16_t*)xbf, (const bf16_t*)(ipwbf + (size_t)DINNER * DMODEL),
            ipb + DINNER, nullptr, S5, nullptr, nullptr, nullptr,
            DMODEL, DINNER, Lc, SEQ, l0, Lc, 0, EP_SIG);
        // 9. replay + y = (ct*st + D*u)*sig -> ybf (in place over S4)
        p3y_v4<<<scanBlocks, blk, 0, stream>>>(S3, S4, S1, S2, S5, dpar, Pb, Lc, nsub);
        // 10. out = ybf @ ow^T + ob  (f32)
        gemm_bf16_ep<<<gOut, blk, 0, stream>>>(
            (const bf16_t*)S4, (const bf16_t*)owbf, ob, out, nullptr,
            nullptr, nullptr, nullptr,
            DINNER, DMODEL, Lc, Lc, 0, SEQ, l0, EP_F32);
    }
}

// Round 5
// 1192.590 us; speedup vs baseline: 6.3268x; 1.0987x over previous
//
#include <hip/hip_runtime.h>
#include <math.h>
#include <stdint.h>

// Mamba2-lite mixer, round 5: fused-operand GEMMs (XZ: N=4096, DBC: N=6144),
// XCD-aware swizzle, Lc capped at 2048, bf16 activations end-to-end.
// B=4, L=4096, Dm=1024, Di=2048, K=4.

#define BATCH 4
#define SEQ 4096
#define DMODEL 1024
#define DINNER 2048
#define CLS 32          // scan sub-chunk length

typedef __bf16 bf16_t;
typedef __bf16 bf16x8 __attribute__((ext_vector_type(8)));
typedef float f32x4 __attribute__((ext_vector_type(4)));
typedef unsigned short ushort_t;
typedef unsigned short u16x4 __attribute__((ext_vector_type(4)));

enum { EP_F32 = 0, EP_XZ = 1, EP_DBC = 2 };

__device__ __forceinline__ void gload_lds16(const void* g, void* l) {
    __builtin_amdgcn_global_load_lds(
        (const __attribute__((address_space(1))) void*)g,
        (__attribute__((address_space(3))) void*)l, 16, 0, 0);
}

__device__ __forceinline__ ushort_t f2bf(float f) {
    union { float f; uint32_t u; } c; c.f = f;
    uint32_t u = c.u;
    u += 0x7fffu + ((u >> 16) & 1u);          // RNE
    return (ushort_t)(u >> 16);
}
__device__ __forceinline__ float bf2f(ushort_t h) {
    union { uint32_t u; float f; } c; c.u = (uint32_t)h << 16;
    return c.f;
}
__device__ __forceinline__ float tanh_fast(float v) {
    v = fminf(fmaxf(v, -15.f), 15.f);
    float e = __expf(2.f * v);
    return (e - 1.f) / (e + 1.f);
}

// ---------------- bf16 MFMA GEMM with fused multi-target epilogues -------
// C[m,n] = sum_k A[m,k]*W[n,k]. 128x128 tile, BK=64, 4 waves, 16x16x32
// MFMA, XOR-swizzled LDS via pre-swizzled global source (rule #21).
// Grid is XCD-swizzled (bijective, m204) so consecutive n-blocks of one
// A-panel share an XCD's L2.
#define GBK 64

__global__ __launch_bounds__(256) void gemm_bf16_ep(
    const bf16_t* __restrict__ A, const bf16_t* __restrict__ W,
    const float* __restrict__ bias,
    float* __restrict__ Cf, ushort_t* __restrict__ T0,
    ushort_t* __restrict__ T1, ushort_t* __restrict__ T2,
    const float* __restrict__ alogp,
    int K, int Nout, int Lc, int a_bstride, int a_l0,
    int c_bstride, int c_l0, int mode)
{
    __shared__ __align__(16) bf16_t sA[128 * GBK];   // 16 KB
    __shared__ __align__(16) bf16_t sB[128 * GBK];   // 16 KB
    // ---- bijective XCD swizzle ----
    const int nwg = gridDim.x * gridDim.y;
    int bid = blockIdx.y * gridDim.x + blockIdx.x;
    {
        int q = nwg >> 3, r = nwg & 7;
        int xcd = bid & 7, sid = bid >> 3;
        bid = (xcd < r ? xcd * (q + 1) : r * (q + 1) + (xcd - r) * q) + sid;
    }
    const int bx = bid % gridDim.x;
    const int by = bid / gridDim.x;

    const int tid = threadIdx.x;
    const int lane = tid & 63;
    const int wid = tid >> 6;
    const int wm = wid >> 1, wn = wid & 1;
    const int n0 = bx * 128;
    const int m0 = by * 128;
    const int bb = m0 / Lc;
    const int lb = m0 - bb * Lc;
    const bf16_t* Abase = A + ((size_t)bb * a_bstride + a_l0 + lb) * K;
    const bf16_t* Wbase = W + (size_t)n0 * K;

    int st_row[4], st_sc[4], st_ofs[4];
#pragma unroll
    for (int i = 0; i < 4; ++i) {
        int ofs = tid * 16 + i * 4096;
        int r = ofs >> 7;
        int c16 = (ofs >> 4) & 7;
        st_ofs[i] = ofs;
        st_row[i] = r;
        st_sc[i] = (c16 ^ (r & 7)) << 3;
    }

    f32x4 acc[4][4];
#pragma unroll
    for (int i = 0; i < 4; ++i)
#pragma unroll
        for (int j = 0; j < 4; ++j) acc[i][j] = f32x4{0.f, 0.f, 0.f, 0.f};

    for (int k0 = 0; k0 < K; k0 += GBK) {
#pragma unroll
        for (int i = 0; i < 4; ++i) {
            gload_lds16(Abase + (size_t)st_row[i] * K + k0 + st_sc[i],
                        (char*)sA + st_ofs[i]);
            gload_lds16(Wbase + (size_t)st_row[i] * K + k0 + st_sc[i],
                        (char*)sB + st_ofs[i]);
        }
        __syncthreads();
#pragma unroll
        for (int ks = 0; ks < 2; ++ks) {
            bf16x8 av[4], bv[4];
#pragma unroll
            for (int mi = 0; mi < 4; ++mi) {
                int row = wm * 64 + mi * 16 + (lane & 15);
                int cb = (ks * 64 + ((lane >> 4) << 4)) ^ ((row & 7) << 4);
                av[mi] = *(const bf16x8*)((const char*)sA + row * 128 + cb);
            }
#pragma unroll
            for (int ni = 0; ni < 4; ++ni) {
                int row = wn * 64 + ni * 16 + (lane & 15);
                int cb = (ks * 64 + ((lane >> 4) << 4)) ^ ((row & 7) << 4);
                bv[ni] = *(const bf16x8*)((const char*)sB + row * 128 + cb);
            }
#pragma unroll
            for (int mi = 0; mi < 4; ++mi)
#pragma unroll
                for (int ni = 0; ni < 4; ++ni)
                    acc[mi][ni] = __builtin_amdgcn_mfma_f32_16x16x32_bf16(
                        av[mi], bv[ni], acc[mi][ni], 0, 0, 0);
        }
        __syncthreads();
    }

    // ---- fused epilogue (column-group dispatch; n0 is 128-aligned so the
    // 2048-boundary group is block-uniform) ----
    const int grp = n0 >> 11;          // 0.. (Nlogical/2048 - 1)
    const int nloc = n0 & 2047;
    const size_t rowbase = (size_t)bb * c_bstride + c_l0 + lb;
#pragma unroll
    for (int ni = 0; ni < 4; ++ni) {
        const int coll = wn * 64 + ni * 16 + (lane & 15);
        const int colg = nloc + coll;              // col within 2048-group
        float bv = 0.f, Ae = 0.f;
        if (mode == EP_XZ)  bv = bias[n0 + coll];
        else if (mode == EP_DBC) {
            if (grp == 0) { bv = bias[colg]; Ae = __expf(alogp[colg]); }
        } else if (bias) bv = bias[n0 + coll];
#pragma unroll
        for (int mi = 0; mi < 4; ++mi) {
#pragma unroll
            for (int r4 = 0; r4 < 4; ++r4) {
                const int rowl = wm * 64 + mi * 16 + ((lane >> 4) << 2) + r4;
                const size_t off = (rowbase + rowl) * (size_t)Nout + colg;
                float v = acc[mi][ni][r4] + bv;
                if (mode == EP_F32) {
                    Cf[off] = v;
                } else if (mode == EP_XZ) {
                    if (grp == 0) T0[off] = f2bf(v);                      // xb
                    else          T1[off] = f2bf(1.f / (1.f + __expf(-v))); // sig(z)
                } else {  // EP_DBC
                    if (grp == 0) {
                        float sp = fmaxf(v, 0.f) + __logf(1.f + __expf(-fabsf(v)));
                        T0[off] = f2bf(__expf(-(sp + 1e-4f) * Ae));       // decay
                    } else if (grp == 1) {
                        T1[off] = f2bf(tanh_fast(v));                     // bt
                    } else {
                        T2[off] = f2bf(tanh_fast(v));                     // ct
                    }
                }
            }
        }
    }
}

// ---------------- f32 -> bf16 conversion (one-time) ----------------------
__global__ __launch_bounds__(256) void cvt_bf16_k(
    const float4* __restrict__ in, ushort4* __restrict__ out, int n4)
{
    for (int i = blockIdx.x * 256 + threadIdx.x; i < n4; i += gridDim.x * 256) {
        float4 v = in[i];
        ushort4 o;
        o.x = f2bf(v.x); o.y = f2bf(v.y); o.z = f2bf(v.z); o.w = f2bf(v.w);
        out[i] = o;
    }
}

// ---------------- causal depthwise conv1d (k=4) + SiLU, bf16 ------------
__global__ __launch_bounds__(256) void conv_silu_bf(
    const ushort_t* __restrict__ xb, const ushort_t* __restrict__ tailb,
    const float* __restrict__ cw, const float* __restrict__ cb,
    ushort_t* __restrict__ ubf, int Lc, int l0, size_t total)
{
    for (size_t idx = (size_t)blockIdx.x * 256 + threadIdx.x; idx < total;
         idx += (size_t)gridDim.x * 256) {
        int e = (int)(idx % DINNER);
        size_t r = idx / DINNER;
        int lp = (int)(r % Lc);
        int b  = (int)(r / Lc);
        float4 w = *(const float4*)(cw + (size_t)e * 4);
        float s = cb[e];
        const ushort_t* xbase = xb + (size_t)b * Lc * DINNER + e;
        if (lp >= 3) {
            s += bf2f(xbase[(size_t)(lp - 3) * DINNER]) * w.x
               + bf2f(xbase[(size_t)(lp - 2) * DINNER]) * w.y
               + bf2f(xbase[(size_t)(lp - 1) * DINNER]) * w.z
               + bf2f(xbase[(size_t)lp * DINNER]) * w.w;
        } else {
            const float ws4[4] = {w.x, w.y, w.z, w.w};
            const ushort_t* tbase = tailb + (size_t)b * 3 * DINNER + e;
#pragma unroll
            for (int j = 0; j < 4; ++j) {
                int ls = lp - 3 + j;
                float v;
                if (ls >= 0)            v = bf2f(xbase[(size_t)ls * DINNER]);
                else if (l0 + ls >= 0)  v = bf2f(tbase[(size_t)(3 + ls) * DINNER]);
                else                    v = 0.f;
                s += v * ws4[j];
            }
        }
        ubf[idx] = f2bf(s / (1.f + __expf(-s)));
    }
}

__global__ __launch_bounds__(256) void tail_update_bf(
    const ushort_t* __restrict__ xb, ushort_t* __restrict__ tailb, int Lc)
{
    int idx = blockIdx.x * 256 + threadIdx.x;     // BATCH*3*DINNER
    if (idx >= BATCH * 3 * DINNER) return;
    int e = idx % DINNER;
    int j = (idx / DINNER) % 3;
    int b = idx / (3 * DINNER);
    tailb[idx] = xb[((size_t)b * Lc + Lc - 3 + j) * DINNER + e];
}

// ---------------- scan phase1: inc=(1-d)*bt*u on the fly, x4 ------------
__global__ __launch_bounds__(256) void scan1_v4(
    const ushort_t* __restrict__ dec, const ushort_t* __restrict__ bt,
    const ushort_t* __restrict__ ub,
    float* __restrict__ P, float* __restrict__ S, int Lc, int nsub)
{
    int t = blockIdx.x * 256 + threadIdx.x;    // BATCH*nsub*512 threads
    int e = (t & 511) << 2;
    int rest = t >> 9;
    int c = rest % nsub;
    int b = rest / nsub;
    size_t off = ((size_t)b * Lc + (size_t)c * CLS) * DINNER + e;
    float p[4] = {1.f, 1.f, 1.f, 1.f};
    float s[4] = {0.f, 0.f, 0.f, 0.f};
    for (int t0 = 0; t0 < CLS; ++t0) {
        size_t o = off + (size_t)t0 * DINNER;
        u16x4 d4 = *(const u16x4*)(dec + o);
        u16x4 b4 = *(const u16x4*)(bt + o);
        u16x4 u4 = *(const u16x4*)(ub + o);
#pragma unroll
        for (int j = 0; j < 4; ++j) {
            float d = bf2f(d4[j]);
            float inc = (1.f - d) * bf2f(b4[j]) * bf2f(u4[j]);
            s[j] = d * s[j] + inc;
            p[j] *= d;
        }
    }
    size_t po = ((size_t)b * nsub + c) * DINNER + e;
    *(float4*)(P + po) = float4{p[0], p[1], p[2], p[3]};
    *(float4*)(S + po) = float4{s[0], s[1], s[2], s[3]};
}

// ---------------- scan phase2: sequential combine over sub-chunks -------
__global__ __launch_bounds__(256) void scan_p2(
    float* __restrict__ P, float* __restrict__ S,
    float* __restrict__ carry, int nsub, int first)
{
    int idx = blockIdx.x * 256 + threadIdx.x;   // BATCH*DINNER
    int e = idx % DINNER;
    int b = idx / DINNER;
    float cv = first ? 0.f : carry[idx];
    for (int c = 0; c < nsub; ++c) {
        size_t o = ((size_t)b * nsub + c) * DINNER + e;
        float p = P[o], s = S[o];
        P[o] = cv;
        cv = p * cv + s;
    }
    carry[idx] = cv;
}

// ---------------- phase3 fused: replay + y=(ct*st+D*u)*sig -> bf16 ------
// bt buffer is overwritten in place with ybf.
__global__ __launch_bounds__(256) void p3y_v4(
    const ushort_t* __restrict__ dec, ushort_t* __restrict__ bty,
    const ushort_t* __restrict__ ct, const ushort_t* __restrict__ ub,
    const ushort_t* __restrict__ sg, const float* __restrict__ Dp,
    const float* __restrict__ Pc, int Lc, int nsub)
{
    int t = blockIdx.x * 256 + threadIdx.x;    // BATCH*nsub*512 threads
    int e = (t & 511) << 2;
    int rest = t >> 9;
    int c = rest % nsub;
    int b = rest / nsub;
    size_t off = ((size_t)b * Lc + (size_t)c * CLS) * DINNER + e;
    size_t po = ((size_t)b * nsub + c) * DINNER + e;
    float4 stv = *(const float4*)(Pc + po);
    float4 Dv  = *(const float4*)(Dp + e);
    float st[4] = {stv.x, stv.y, stv.z, stv.w};
    float D4[4] = {Dv.x, Dv.y, Dv.z, Dv.w};
    for (int t0 = 0; t0 < CLS; ++t0) {
        size_t o = off + (size_t)t0 * DINNER;
        u16x4 d4 = *(const u16x4*)(dec + o);
        u16x4 b4 = *(const u16x4*)(bty + o);
        u16x4 c4 = *(const u16x4*)(ct + o);
        u16x4 u4 = *(const u16x4*)(ub + o);
        u16x4 g4 = *(const u16x4*)(sg + o);
        u16x4 y4;
#pragma unroll
        for (int j = 0; j < 4; ++j) {
            float d = bf2f(d4[j]);
            float u = bf2f(u4[j]);
            float inc = (1.f - d) * bf2f(b4[j]) * u;
            st[j] = d * st[j] + inc;
            float y = bf2f(c4[j]) * st[j] + D4[j] * u;
            y4[j] = f2bf(y * bf2f(g4[j]));
        }
        *(u16x4*)(bty + o) = y4;
    }
}

extern "C" void kernel_launch(void* const* d_in, const int* in_sizes, int n_in,
                              void* d_out, int out_size, void* d_ws, size_t ws_size,
                              hipStream_t stream)
{
    const float* x    = (const float*)d_in[0];
    const float* ipw  = (const float*)d_in[1];
    const float* ipb  = (const float*)d_in[2];
    const float* cw   = (const float*)d_in[3];
    const float* cb   = (const float*)d_in[4];
    const float* dtw  = (const float*)d_in[5];
    const float* dtb  = (const float*)d_in[6];
    const float* bw   = (const float*)d_in[7];
    const float* cwt  = (const float*)d_in[8];
    const float* alog = (const float*)d_in[9];
    const float* dpar = (const float*)d_in[10];
    const float* ow   = (const float*)d_in[11];
    const float* ob   = (const float*)d_in[12];
    float* out = (float*)d_out;

    const size_t XN   = (size_t)BATCH * SEQ * DMODEL;
    const size_t WIP  = (size_t)2 * DINNER * DMODEL;
    const size_t WSQ  = (size_t)DINNER * DINNER;
    const size_t WOUT = (size_t)DMODEL * DINNER;
    const size_t const_bytes = 2 * (XN + WIP + 3 * WSQ + WOUT);

    // ---- choose Lc (max 2048: keeps GEMMs in the low-overfetch regime) ----
    const int cands[5] = {2048, 1024, 512, 256, 128};
    int Lc = 128;
    for (int i = 0; i < 5; ++i) {
        size_t NBe = (size_t)BATCH * cands[i] * DINNER;
        size_t need = const_bytes
                    + 5 * NBe * 2
                    + (size_t)BATCH * 3 * DINNER * 2
                    + (size_t)BATCH * DINNER * 4
                    + 2 * (size_t)BATCH * (cands[i] / CLS) * DINNER * 4
                    + 1024;
        if (need <= ws_size) { Lc = cands[i]; break; }
    }
    const int nsub = Lc / CLS;
    const size_t NBe = (size_t)BATCH * Lc * DINNER;

    // ---- workspace layout ----
    char* p = (char*)d_ws;
    ushort_t* xbf   = (ushort_t*)p; p += XN * 2;
    ushort_t* ipwbf = (ushort_t*)p; p += WIP * 2;
    ushort_t* wcat  = (ushort_t*)p; p += 3 * WSQ * 2;   // [dtw; bw; cw]
    ushort_t* owbf  = (ushort_t*)p; p += WOUT * 2;
    ushort_t* S1 = (ushort_t*)p; p += NBe * 2;   // xb -> ct
    ushort_t* S2 = (ushort_t*)p; p += NBe * 2;   // u
    ushort_t* S3 = (ushort_t*)p; p += NBe * 2;   // decay
    ushort_t* S4 = (ushort_t*)p; p += NBe * 2;   // bt -> ybf
    ushort_t* S5 = (ushort_t*)p; p += NBe * 2;   // sigmoid(z)
    ushort_t* tailb = (ushort_t*)p; p += (size_t)BATCH * 3 * DINNER * 2;
    float* carry = (float*)p; p += (size_t)BATCH * DINNER * 4;
    float* Pb    = (float*)p; p += (size_t)BATCH * nsub * DINNER * 4;
    float* Sb    = (float*)p;

    const dim3 blk(256);
    const int M = BATCH * Lc;
    const dim3 gXZ(2 * DINNER / 128, M / 128);
    const dim3 gDBC(3 * DINNER / 128, M / 128);
    const dim3 gOut(DMODEL / 128, M / 128);
    const int pwBlocks = (int)(((NBe + 255) / 256 < 4096) ? (NBe + 255) / 256 : 4096);
    const int scanBlocks = BATCH * nsub * 2;     // x4 vectorized, 512 thr/(b,c)

    auto cvt = [&](const float* in, ushort_t* outp, size_t n) {
        int n4 = (int)(n / 4);
        int g = n4 / 256 < 2048 ? (n4 + 255) / 256 : 2048;
        cvt_bf16_k<<<g, blk, 0, stream>>>((const float4*)in, (ushort4*)outp, n4);
    };
    cvt(x, xbf, XN);
    cvt(ipw, ipwbf, WIP);
    cvt(dtw, wcat, WSQ);
    cvt(bw, wcat + WSQ, WSQ);
    cvt(cwt, wcat + 2 * WSQ, WSQ);
    cvt(ow, owbf, WOUT);

    const int nchunks = SEQ / Lc;
    for (int c = 0; c < nchunks; ++c) {
        const int l0 = c * Lc;
        // 1. [xb | sig(z)] = x @ ipw^T + ipb   (single A-fetch)
        gemm_bf16_ep<<<gXZ, blk, 0, stream>>>(
            (const bf16_t*)xbf, (const bf16_t*)ipwbf, ipb,
            nullptr, S1, S5, nullptr, nullptr,
            DMODEL, DINNER, Lc, SEQ, l0, Lc, 0, EP_XZ);
        // 2. u = silu(conv(xb))
        conv_silu_bf<<<pwBlocks, blk, 0, stream>>>(S1, tailb, cw, cb, S2, Lc, l0, NBe);
        tail_update_bf<<<BATCH * 3 * DINNER / 256, blk, 0, stream>>>(S1, tailb, Lc);
        // 3. [decay | bt | ct] = epilogues of u @ [dtw;bw;cw]^T  (single A-fetch)
        gemm_bf16_ep<<<gDBC, blk, 0, stream>>>(
            (const bf16_t*)S2, (const bf16_t*)wcat, dtb,
            nullptr, S3, S4, S1, alog,
            DINNER, DINNER, Lc, Lc, 0, Lc, 0, EP_DBC);
        // 4-5. scan partials + combine (inc computed on the fly)
        scan1_v4<<<scanBlocks, blk, 0, stream>>>(S3, S4, S2, Pb, Sb, Lc, nsub);
        scan_p2<<<BATCH * DINNER / 256, blk, 0, stream>>>(Pb, Sb, carry, nsub, c == 0);
        // 6. replay + y = (ct*st + D*u)*sig -> ybf (in place over S4)
        p3y_v4<<<scanBlocks, blk, 0, stream>>>(S3, S4, S1, S2, S5, dpar, Pb, Lc, nsub);
        // 7. out = ybf @ ow^T + ob  (f32)
        gemm_bf16_ep<<<gOut, blk, 0, stream>>>(
            (const bf16_t*)S4, (const bf16_t*)owbf, ob,
            out, nullptr, nullptr, nullptr, nullptr,
            DINNER, DMODEL, Lc, Lc, 0, SEQ, l0, EP_F32);
    }
}

// Round 6
// 1165.234 us; speedup vs baseline: 6.4754x; 1.0235x over previous
//
#include <hip/hip_runtime.h>
#include <math.h>
#include <stdint.h>

// Mamba2-lite mixer, round 6: round-5 structure with the XCD swizzle
// REVERTED (natural dispatch round-robin gives each XCD a persistent
// L2-resident W-slice for these tall-M GEMMs; chunked swizzle forced
// full-W sweeps per by-row -> 696 MB fetch, 340 us. Measured r5 vs r3.)
// B=4, L=4096, Dm=1024, Di=2048, K=4.

#define BATCH 4
#define SEQ 4096
#define DMODEL 1024
#define DINNER 2048
#define CLS 32          // scan sub-chunk length

typedef __bf16 bf16_t;
typedef __bf16 bf16x8 __attribute__((ext_vector_type(8)));
typedef float f32x4 __attribute__((ext_vector_type(4)));
typedef unsigned short ushort_t;
typedef unsigned short u16x4 __attribute__((ext_vector_type(4)));

enum { EP_F32 = 0, EP_XZ = 1, EP_DBC = 2 };

__device__ __forceinline__ void gload_lds16(const void* g, void* l) {
    __builtin_amdgcn_global_load_lds(
        (const __attribute__((address_space(1))) void*)g,
        (__attribute__((address_space(3))) void*)l, 16, 0, 0);
}

__device__ __forceinline__ ushort_t f2bf(float f) {
    union { float f; uint32_t u; } c; c.f = f;
    uint32_t u = c.u;
    u += 0x7fffu + ((u >> 16) & 1u);          // RNE
    return (ushort_t)(u >> 16);
}
__device__ __forceinline__ float bf2f(ushort_t h) {
    union { uint32_t u; float f; } c; c.u = (uint32_t)h << 16;
    return c.f;
}
__device__ __forceinline__ float tanh_fast(float v) {
    v = fminf(fmaxf(v, -15.f), 15.f);
    float e = __expf(2.f * v);
    return (e - 1.f) / (e + 1.f);
}

// ---------------- bf16 MFMA GEMM with fused multi-target epilogues -------
// C[m,n] = sum_k A[m,k]*W[n,k]. 128x128 tile, BK=64, 4 waves, 16x16x32
// MFMA, XOR-swizzled LDS via pre-swizzled global source (rule #21).
// NATURAL blockIdx order: default round-robin across XCDs slices the W
// (n) axis per XCD -> persistent L2-resident W slice (measured r3: 70 MB
// fetch; chunked XCD swizzle ballooned it to 696 MB in r5).
#define GBK 64

__global__ __launch_bounds__(256) void gemm_bf16_ep(
    const bf16_t* __restrict__ A, const bf16_t* __restrict__ W,
    const float* __restrict__ bias,
    float* __restrict__ Cf, ushort_t* __restrict__ T0,
    ushort_t* __restrict__ T1, ushort_t* __restrict__ T2,
    const float* __restrict__ alogp,
    int K, int Nout, int Lc, int a_bstride, int a_l0,
    int c_bstride, int c_l0, int mode)
{
    __shared__ __align__(16) bf16_t sA[128 * GBK];   // 16 KB
    __shared__ __align__(16) bf16_t sB[128 * GBK];   // 16 KB
    const int tid = threadIdx.x;
    const int lane = tid & 63;
    const int wid = tid >> 6;
    const int wm = wid >> 1, wn = wid & 1;
    const int n0 = blockIdx.x * 128;
    const int m0 = blockIdx.y * 128;
    const int bb = m0 / Lc;
    const int lb = m0 - bb * Lc;
    const bf16_t* Abase = A + ((size_t)bb * a_bstride + a_l0 + lb) * K;
    const bf16_t* Wbase = W + (size_t)n0 * K;

    int st_row[4], st_sc[4], st_ofs[4];
#pragma unroll
    for (int i = 0; i < 4; ++i) {
        int ofs = tid * 16 + i * 4096;
        int r = ofs >> 7;
        int c16 = (ofs >> 4) & 7;
        st_ofs[i] = ofs;
        st_row[i] = r;
        st_sc[i] = (c16 ^ (r & 7)) << 3;
    }

    f32x4 acc[4][4];
#pragma unroll
    for (int i = 0; i < 4; ++i)
#pragma unroll
        for (int j = 0; j < 4; ++j) acc[i][j] = f32x4{0.f, 0.f, 0.f, 0.f};

    for (int k0 = 0; k0 < K; k0 += GBK) {
#pragma unroll
        for (int i = 0; i < 4; ++i) {
            gload_lds16(Abase + (size_t)st_row[i] * K + k0 + st_sc[i],
                        (char*)sA + st_ofs[i]);
            gload_lds16(Wbase + (size_t)st_row[i] * K + k0 + st_sc[i],
                        (char*)sB + st_ofs[i]);
        }
        __syncthreads();
#pragma unroll
        for (int ks = 0; ks < 2; ++ks) {
            bf16x8 av[4], bv[4];
#pragma unroll
            for (int mi = 0; mi < 4; ++mi) {
                int row = wm * 64 + mi * 16 + (lane & 15);
                int cb = (ks * 64 + ((lane >> 4) << 4)) ^ ((row & 7) << 4);
                av[mi] = *(const bf16x8*)((const char*)sA + row * 128 + cb);
            }
#pragma unroll
            for (int ni = 0; ni < 4; ++ni) {
                int row = wn * 64 + ni * 16 + (lane & 15);
                int cb = (ks * 64 + ((lane >> 4) << 4)) ^ ((row & 7) << 4);
                bv[ni] = *(const bf16x8*)((const char*)sB + row * 128 + cb);
            }
#pragma unroll
            for (int mi = 0; mi < 4; ++mi)
#pragma unroll
                for (int ni = 0; ni < 4; ++ni)
                    acc[mi][ni] = __builtin_amdgcn_mfma_f32_16x16x32_bf16(
                        av[mi], bv[ni], acc[mi][ni], 0, 0, 0);
        }
        __syncthreads();
    }

    // ---- fused epilogue (column-group dispatch; n0 is 128-aligned so the
    // 2048-boundary group is block-uniform) ----
    const int grp = n0 >> 11;          // 0.. (Nlogical/2048 - 1)
    const int nloc = n0 & 2047;
    const size_t rowbase = (size_t)bb * c_bstride + c_l0 + lb;
#pragma unroll
    for (int ni = 0; ni < 4; ++ni) {
        const int coll = wn * 64 + ni * 16 + (lane & 15);
        const int colg = nloc + coll;              // col within 2048-group
        float bv = 0.f, Ae = 0.f;
        if (mode == EP_XZ)  bv = bias[n0 + coll];
        else if (mode == EP_DBC) {
            if (grp == 0) { bv = bias[colg]; Ae = __expf(alogp[colg]); }
        } else if (bias) bv = bias[n0 + coll];
#pragma unroll
        for (int mi = 0; mi < 4; ++mi) {
#pragma unroll
            for (int r4 = 0; r4 < 4; ++r4) {
                const int rowl = wm * 64 + mi * 16 + ((lane >> 4) << 2) + r4;
                const size_t off = (rowbase + rowl) * (size_t)Nout + colg;
                float v = acc[mi][ni][r4] + bv;
                if (mode == EP_F32) {
                    Cf[off] = v;
                } else if (mode == EP_XZ) {
                    if (grp == 0) T0[off] = f2bf(v);                        // xb
                    else          T1[off] = f2bf(1.f / (1.f + __expf(-v))); // sig(z)
                } else {  // EP_DBC
                    if (grp == 0) {
                        float sp = fmaxf(v, 0.f) + __logf(1.f + __expf(-fabsf(v)));
                        T0[off] = f2bf(__expf(-(sp + 1e-4f) * Ae));         // decay
                    } else if (grp == 1) {
                        T1[off] = f2bf(tanh_fast(v));                       // bt
                    } else {
                        T2[off] = f2bf(tanh_fast(v));                       // ct
                    }
                }
            }
        }
    }
}

// ---------------- f32 -> bf16 conversion (one-time) ----------------------
__global__ __launch_bounds__(256) void cvt_bf16_k(
    const float4* __restrict__ in, ushort4* __restrict__ out, int n4)
{
    for (int i = blockIdx.x * 256 + threadIdx.x; i < n4; i += gridDim.x * 256) {
        float4 v = in[i];
        ushort4 o;
        o.x = f2bf(v.x); o.y = f2bf(v.y); o.z = f2bf(v.z); o.w = f2bf(v.w);
        out[i] = o;
    }
}

// ---------------- causal depthwise conv1d (k=4) + SiLU, bf16 ------------
__global__ __launch_bounds__(256) void conv_silu_bf(
    const ushort_t* __restrict__ xb, const ushort_t* __restrict__ tailb,
    const float* __restrict__ cw, const float* __restrict__ cb,
    ushort_t* __restrict__ ubf, int Lc, int l0, size_t total)
{
    for (size_t idx = (size_t)blockIdx.x * 256 + threadIdx.x; idx < total;
         idx += (size_t)gridDim.x * 256) {
        int e = (int)(idx % DINNER);
        size_t r = idx / DINNER;
        int lp = (int)(r % Lc);
        int b  = (int)(r / Lc);
        float4 w = *(const float4*)(cw + (size_t)e * 4);
        float s = cb[e];
        const ushort_t* xbase = xb + (size_t)b * Lc * DINNER + e;
        if (lp >= 3) {
            s += bf2f(xbase[(size_t)(lp - 3) * DINNER]) * w.x
               + bf2f(xbase[(size_t)(lp - 2) * DINNER]) * w.y
               + bf2f(xbase[(size_t)(lp - 1) * DINNER]) * w.z
               + bf2f(xbase[(size_t)lp * DINNER]) * w.w;
        } else {
            const float ws4[4] = {w.x, w.y, w.z, w.w};
            const ushort_t* tbase = tailb + (size_t)b * 3 * DINNER + e;
#pragma unroll
            for (int j = 0; j < 4; ++j) {
                int ls = lp - 3 + j;
                float v;
                if (ls >= 0)            v = bf2f(xbase[(size_t)ls * DINNER]);
                else if (l0 + ls >= 0)  v = bf2f(tbase[(size_t)(3 + ls) * DINNER]);
                else                    v = 0.f;
                s += v * ws4[j];
            }
        }
        ubf[idx] = f2bf(s / (1.f + __expf(-s)));
    }
}

__global__ __launch_bounds__(256) void tail_update_bf(
    const ushort_t* __restrict__ xb, ushort_t* __restrict__ tailb, int Lc)
{
    int idx = blockIdx.x * 256 + threadIdx.x;     // BATCH*3*DINNER
    if (idx >= BATCH * 3 * DINNER) return;
    int e = idx % DINNER;
    int j = (idx / DINNER) % 3;
    int b = idx / (3 * DINNER);
    tailb[idx] = xb[((size_t)b * Lc + Lc - 3 + j) * DINNER + e];
}

// ---------------- scan phase1: inc=(1-d)*bt*u on the fly, x4 ------------
__global__ __launch_bounds__(256) void scan1_v4(
    const ushort_t* __restrict__ dec, const ushort_t* __restrict__ bt,
    const ushort_t* __restrict__ ub,
    float* __restrict__ P, float* __restrict__ S, int Lc, int nsub)
{
    int t = blockIdx.x * 256 + threadIdx.x;    // BATCH*nsub*512 threads
    int e = (t & 511) << 2;
    int rest = t >> 9;
    int c = rest % nsub;
    int b = rest / nsub;
    size_t off = ((size_t)b * Lc + (size_t)c * CLS) * DINNER + e;
    float p[4] = {1.f, 1.f, 1.f, 1.f};
    float s[4] = {0.f, 0.f, 0.f, 0.f};
    for (int t0 = 0; t0 < CLS; ++t0) {
        size_t o = off + (size_t)t0 * DINNER;
        u16x4 d4 = *(const u16x4*)(dec + o);
        u16x4 b4 = *(const u16x4*)(bt + o);
        u16x4 u4 = *(const u16x4*)(ub + o);
#pragma unroll
        for (int j = 0; j < 4; ++j) {
            float d = bf2f(d4[j]);
            float inc = (1.f - d) * bf2f(b4[j]) * bf2f(u4[j]);
            s[j] = d * s[j] + inc;
            p[j] *= d;
        }
    }
    size_t po = ((size_t)b * nsub + c) * DINNER + e;
    *(float4*)(P + po) = float4{p[0], p[1], p[2], p[3]};
    *(float4*)(S + po) = float4{s[0], s[1], s[2], s[3]};
}

// ---------------- scan phase2: sequential combine over sub-chunks -------
__global__ __launch_bounds__(256) void scan_p2(
    float* __restrict__ P, float* __restrict__ S,
    float* __restrict__ carry, int nsub, int first)
{
    int idx = blockIdx.x * 256 + threadIdx.x;   // BATCH*DINNER
    int e = idx % DINNER;
    int b = idx / DINNER;
    float cv = first ? 0.f : carry[idx];
    for (int c = 0; c < nsub; ++c) {
        size_t o = ((size_t)b * nsub + c) * DINNER + e;
        float p = P[o], s = S[o];
        P[o] = cv;
        cv = p * cv + s;
    }
    carry[idx] = cv;
}

// ---------------- phase3 fused: replay + y=(ct*st+D*u)*sig -> bf16 ------
// bt buffer is overwritten in place with ybf.
__global__ __launch_bounds__(256) void p3y_v4(
    const ushort_t* __restrict__ dec, ushort_t* __restrict__ bty,
    const ushort_t* __restrict__ ct, const ushort_t* __restrict__ ub,
    const ushort_t* __restrict__ sg, const float* __restrict__ Dp,
    const float* __restrict__ Pc, int Lc, int nsub)
{
    int t = blockIdx.x * 256 + threadIdx.x;    // BATCH*nsub*512 threads
    int e = (t & 511) << 2;
    int rest = t >> 9;
    int c = rest % nsub;
    int b = rest / nsub;
    size_t off = ((size_t)b * Lc + (size_t)c * CLS) * DINNER + e;
    size_t po = ((size_t)b * nsub + c) * DINNER + e;
    float4 stv = *(const float4*)(Pc + po);
    float4 Dv  = *(const float4*)(Dp + e);
    float st[4] = {stv.x, stv.y, stv.z, stv.w};
    float D4[4] = {Dv.x, Dv.y, Dv.z, Dv.w};
    for (int t0 = 0; t0 < CLS; ++t0) {
        size_t o = off + (size_t)t0 * DINNER;
        u16x4 d4 = *(const u16x4*)(dec + o);
        u16x4 b4 = *(const u16x4*)(bty + o);
        u16x4 c4 = *(const u16x4*)(ct + o);
        u16x4 u4 = *(const u16x4*)(ub + o);
        u16x4 g4 = *(const u16x4*)(sg + o);
        u16x4 y4;
#pragma unroll
        for (int j = 0; j < 4; ++j) {
            float d = bf2f(d4[j]);
            float u = bf2f(u4[j]);
            float inc = (1.f - d) * bf2f(b4[j]) * u;
            st[j] = d * st[j] + inc;
            float y = bf2f(c4[j]) * st[j] + D4[j] * u;
            y4[j] = f2bf(y * bf2f(g4[j]));
        }
        *(u16x4*)(bty + o) = y4;
    }
}

extern "C" void kernel_launch(void* const* d_in, const int* in_sizes, int n_in,
                              void* d_out, int out_size, void* d_ws, size_t ws_size,
                              hipStream_t stream)
{
    const float* x    = (const float*)d_in[0];
    const float* ipw  = (const float*)d_in[1];
    const float* ipb  = (const float*)d_in[2];
    const float* cw   = (const float*)d_in[3];
    const float* cb   = (const float*)d_in[4];
    const float* dtw  = (const float*)d_in[5];
    const float* dtb  = (const float*)d_in[6];
    const float* bw   = (const float*)d_in[7];
    const float* cwt  = (const float*)d_in[8];
    const float* alog = (const float*)d_in[9];
    const float* dpar = (const float*)d_in[10];
    const float* ow   = (const float*)d_in[11];
    const float* ob   = (const float*)d_in[12];
    float* out = (float*)d_out;

    const size_t XN   = (size_t)BATCH * SEQ * DMODEL;
    const size_t WIP  = (size_t)2 * DINNER * DMODEL;
    const size_t WSQ  = (size_t)DINNER * DINNER;
    const size_t WOUT = (size_t)DMODEL * DINNER;
    const size_t const_bytes = 2 * (XN + WIP + 3 * WSQ + WOUT);

    // ---- choose Lc (max 2048: keeps GEMMs in the low-overfetch regime) ----
    const int cands[5] = {2048, 1024, 512, 256, 128};
    int Lc = 128;
    for (int i = 0; i < 5; ++i) {
        size_t NBe = (size_t)BATCH * cands[i] * DINNER;
        size_t need = const_bytes
                    + 5 * NBe * 2
                    + (size_t)BATCH * 3 * DINNER * 2
                    + (size_t)BATCH * DINNER * 4
                    + 2 * (size_t)BATCH * (cands[i] / CLS) * DINNER * 4
                    + 1024;
        if (need <= ws_size) { Lc = cands[i]; break; }
    }
    const int nsub = Lc / CLS;
    const size_t NBe = (size_t)BATCH * Lc * DINNER;

    // ---- workspace layout ----
    char* p = (char*)d_ws;
    ushort_t* xbf   = (ushort_t*)p; p += XN * 2;
    ushort_t* ipwbf = (ushort_t*)p; p += WIP * 2;
    ushort_t* wcat  = (ushort_t*)p; p += 3 * WSQ * 2;   // [dtw; bw; cw]
    ushort_t* owbf  = (ushort_t*)p; p += WOUT * 2;
    ushort_t* S1 = (ushort_t*)p; p += NBe * 2;   // xb -> ct
    ushort_t* S2 = (ushort_t*)p; p += NBe * 2;   // u
    ushort_t* S3 = (ushort_t*)p; p += NBe * 2;   // decay
    ushort_t* S4 = (ushort_t*)p; p += NBe * 2;   // bt -> ybf
    ushort_t* S5 = (ushort_t*)p; p += NBe * 2;   // sigmoid(z)
    ushort_t* tailb = (ushort_t*)p; p += (size_t)BATCH * 3 * DINNER * 2;
    float* carry = (float*)p; p += (size_t)BATCH * DINNER * 4;
    float* Pb    = (float*)p; p += (size_t)BATCH * nsub * DINNER * 4;
    float* Sb    = (float*)p;

    const dim3 blk(256);
    const int M = BATCH * Lc;
    const dim3 gXZ(2 * DINNER / 128, M / 128);
    const dim3 gDBC(3 * DINNER / 128, M / 128);
    const dim3 gOut(DMODEL / 128, M / 128);
    const int pwBlocks = (int)(((NBe + 255) / 256 < 4096) ? (NBe + 255) / 256 : 4096);
    const int scanBlocks = BATCH * nsub * 2;     // x4 vectorized, 512 thr/(b,c)

    auto cvt = [&](const float* in, ushort_t* outp, size_t n) {
        int n4 = (int)(n / 4);
        int g = n4 / 256 < 2048 ? (n4 + 255) / 256 : 2048;
        cvt_bf16_k<<<g, blk, 0, stream>>>((const float4*)in, (ushort4*)outp, n4);
    };
    cvt(x, xbf, XN);
    cvt(ipw, ipwbf, WIP);
    cvt(dtw, wcat, WSQ);
    cvt(bw, wcat + WSQ, WSQ);
    cvt(cwt, wcat + 2 * WSQ, WSQ);
    cvt(ow, owbf, WOUT);

    const int nchunks = SEQ / Lc;
    for (int c = 0; c < nchunks; ++c) {
        const int l0 = c * Lc;
        // 1. [xb | sig(z)] = x @ ipw^T + ipb   (single A-fetch)
        gemm_bf16_ep<<<gXZ, blk, 0, stream>>>(
            (const bf16_t*)xbf, (const bf16_t*)ipwbf, ipb,
            nullptr, S1, S5, nullptr, nullptr,
            DMODEL, DINNER, Lc, SEQ, l0, Lc, 0, EP_XZ);
        // 2. u = silu(conv(xb))
        conv_silu_bf<<<pwBlocks, blk, 0, stream>>>(S1, tailb, cw, cb, S2, Lc, l0, NBe);
        tail_update_bf<<<BATCH * 3 * DINNER / 256, blk, 0, stream>>>(S1, tailb, Lc);
        // 3. [decay | bt | ct] = epilogues of u @ [dtw;bw;cw]^T  (single A-fetch)
        gemm_bf16_ep<<<gDBC, blk, 0, stream>>>(
            (const bf16_t*)S2, (const bf16_t*)wcat, dtb,
            nullptr, S3, S4, S1, alog,
            DINNER, DINNER, Lc, Lc, 0, Lc, 0, EP_DBC);
        // 4-5. scan partials + combine (inc computed on the fly)
        scan1_v4<<<scanBlocks, blk, 0, stream>>>(S3, S4, S2, Pb, Sb, Lc, nsub);
        scan_p2<<<BATCH * DINNER / 256, blk, 0, stream>>>(Pb, Sb, carry, nsub, c == 0);
        // 6. replay + y = (ct*st + D*u)*sig -> ybf (in place over S4)
        p3y_v4<<<scanBlocks, blk, 0, stream>>>(S3, S4, S1, S2, S5, dpar, Pb, Lc, nsub);
        // 7. out = ybf @ ow^T + ob  (f32)
        gemm_bf16_ep<<<gOut, blk, 0, stream>>>(
            (const bf16_t*)S4, (const bf16_t*)owbf, ob,
            out, nullptr, nullptr, nullptr, nullptr,
            DINNER, DMODEL, Lc, Lc, 0, SEQ, l0, EP_F32);
    }
}